// Round 10
// baseline (43.050 us; speedup 1.0000x reference)
//
#include <hip/hip_runtime.h>
#include <hip/hip_bf16.h>

#define POOL 7
#define HW 128
#define CH 1024
#define NROI 512
#define NXCD 8
#define CPG 128                       // channels per group (8 groups = 8 XCDs)
#define NUNITS (NROI * POOL)          // 3584 (roi, py) units
#define WPG 896                       // waves per channel-group
#define NBLK_P ((WPG / 4) * NXCD)     // 224 blocks/group * 8 = 1792 blocks

typedef float f4 __attribute__((ext_vector_type(4)));

// ---------------------------------------------------------------------------
// Persistent channel-sliced ROI-align, identity order, f4 two-units-per-wave.
// R9: plain (cached) stores — single-variable A/B vs R8's nontemporal stores.
// ---------------------------------------------------------------------------
__global__ __launch_bounds__(256) void roi_align_kernel(
    const float* __restrict__ img,   // [128][128][1024]
    const int*   __restrict__ rois,  // [512][4] = x,y,w,h
    float*       __restrict__ out)   // [512][7][7][1024]
{
    const int g    = blockIdx.x & (NXCD - 1);    // channel group == XCD
    const int wave = threadIdx.x >> 6;
    const int half = (threadIdx.x >> 5) & 1;     // unit within pair
    const int l    = threadIdx.x & 31;           // lane within half-wave
    const int wid  = ((blockIdx.x >> 3) << 2) + wave;  // 0..895 per group

    const float* gimg = img + g * CPG + l * 4;
    float*       gout = out + g * CPG + l * 4;

#pragma unroll 1
    for (int i = 0; i < 2; ++i) {
        const int p = wid + i * WPG;             // pair id 0..1791
        const int u = 2 * p + half;              // unit 0..3583
        const int r  = u / POOL;
        const int py = u - r * POOL;

        const int4 roi = ((const int4*)rois)[r];
        const int rx = roi.x, ry = roi.y, rw = roi.z, rh = roi.w;

        // y axis sample
        const float hf = (float)rh;
        float cy = ((float)py + 0.5f) * (hf / (float)POOL) - 0.5f;
        cy = fminf(fmaxf(cy, 0.0f), fmaxf(hf - 1.0f, 0.0f));
        const int  iy0 = (int)floorf(cy);
        const int  iy1 = min(iy0 + 1, rh - 1);
        const float ty = cy - (float)iy0;

        const int y0 = ry + iy0, y1 = ry + iy1;
        const float* row0 = gimg + (size_t)y0 * HW * CH;
        const float* row1 = gimg + (size_t)y1 * HW * CH;

        const float wf = (float)rw;
        const float xscale = wf / (float)POOL;

        int   x0a[POOL], x1a[POOL];
        float txa[POOL];
#pragma unroll
        for (int px = 0; px < POOL; ++px) {
            float cx = ((float)px + 0.5f) * xscale - 0.5f;
            cx = fminf(fmaxf(cx, 0.0f), fmaxf(wf - 1.0f, 0.0f));
            const int ix0 = (int)floorf(cx);
            const int ix1 = min(ix0 + 1, rw - 1);
            txa[px] = cx - (float)ix0;
            x0a[px] = rx + ix0;
            x1a[px] = rx + ix1;
        }

        float* obase = gout + ((size_t)r * 49 + (size_t)py * POOL) * CH;

#pragma unroll
        for (int px = 0; px < POOL; ++px) {
            const f4 v00 = *(const f4*)(row0 + (size_t)x0a[px] * CH);
            const f4 v01 = *(const f4*)(row0 + (size_t)x1a[px] * CH);
            const f4 v10 = *(const f4*)(row1 + (size_t)x0a[px] * CH);
            const f4 v11 = *(const f4*)(row1 + (size_t)x1a[px] * CH);
            const float tx = txa[px];
            f4 top = v00 + tx * (v01 - v00);
            f4 bot = v10 + tx * (v11 - v10);
            f4 res = top + ty * (bot - top);
            *(f4*)(obase + (size_t)px * CH) = res;   // plain cached store
        }
    }
}

extern "C" void kernel_launch(void* const* d_in, const int* in_sizes, int n_in,
                              void* d_out, int out_size, void* d_ws, size_t ws_size,
                              hipStream_t stream) {
    const float* img  = (const float*)d_in[0];
    const int*   rois = (const int*)d_in[1];
    float*       out  = (float*)d_out;

    roi_align_kernel<<<NBLK_P, 256, 0, stream>>>(img, rois, out);
}

// Round 11
// 36.293 us; speedup vs baseline: 1.1862x; 1.1862x over previous
//
#include <hip/hip_runtime.h>
#include <hip/hip_bf16.h>

#define POOL 7
#define HW 128
#define CH 1024
#define NROI 512
#define NXCD 8
#define CPG 128                       // channels per group (8 groups = 8 XCDs)
#define NUNITS (NROI * POOL)          // 3584 (roi, py) units
#define WPG 896                       // waves per channel-group
#define NBLK_P ((WPG / 4) * NXCD)     // 224 blocks/group * 8 = 1792 blocks

typedef float f4 __attribute__((ext_vector_type(4)));

// ---------------------------------------------------------------------------
// Persistent channel-sliced ROI-align, identity order, f4 two-units-per-wave,
// nontemporal stores (R8 configuration — best known: 36.5 us).
// blockIdx%8 = channel group g (pinned to hw XCD): each XCD's L2 only sees
// its own 8.4 MB channel slice. Lanes 0-31 handle unit 2p, lanes 32-63 unit
// 2p+1; each half-wave covers the 128-ch slice as 32 lanes x float4.
// NT stores keep the 100 MB output stream from write-allocating in L2/L3
// (R9 A/B: plain stores -> FETCH +25 MB, dur +6.6 us).
// ---------------------------------------------------------------------------
__global__ __launch_bounds__(256) void roi_align_kernel(
    const float* __restrict__ img,   // [128][128][1024]
    const int*   __restrict__ rois,  // [512][4] = x,y,w,h
    float*       __restrict__ out)   // [512][7][7][1024]
{
    const int g    = blockIdx.x & (NXCD - 1);    // channel group == XCD
    const int wave = threadIdx.x >> 6;
    const int half = (threadIdx.x >> 5) & 1;     // unit within pair
    const int l    = threadIdx.x & 31;           // lane within half-wave
    const int wid  = ((blockIdx.x >> 3) << 2) + wave;  // 0..895 per group

    const float* gimg = img + g * CPG + l * 4;
    float*       gout = out + g * CPG + l * 4;

#pragma unroll 1
    for (int i = 0; i < 2; ++i) {
        const int p = wid + i * WPG;             // pair id 0..1791
        const int u = 2 * p + half;              // unit 0..3583
        const int r  = u / POOL;
        const int py = u - r * POOL;

        const int4 roi = ((const int4*)rois)[r];
        const int rx = roi.x, ry = roi.y, rw = roi.z, rh = roi.w;

        // y axis sample
        const float hf = (float)rh;
        float cy = ((float)py + 0.5f) * (hf / (float)POOL) - 0.5f;
        cy = fminf(fmaxf(cy, 0.0f), fmaxf(hf - 1.0f, 0.0f));
        const int  iy0 = (int)floorf(cy);
        const int  iy1 = min(iy0 + 1, rh - 1);
        const float ty = cy - (float)iy0;

        const int y0 = ry + iy0, y1 = ry + iy1;
        const float* row0 = gimg + (size_t)y0 * HW * CH;
        const float* row1 = gimg + (size_t)y1 * HW * CH;

        const float wf = (float)rw;
        const float xscale = wf / (float)POOL;

        int   x0a[POOL], x1a[POOL];
        float txa[POOL];
#pragma unroll
        for (int px = 0; px < POOL; ++px) {
            float cx = ((float)px + 0.5f) * xscale - 0.5f;
            cx = fminf(fmaxf(cx, 0.0f), fmaxf(wf - 1.0f, 0.0f));
            const int ix0 = (int)floorf(cx);
            const int ix1 = min(ix0 + 1, rw - 1);
            txa[px] = cx - (float)ix0;
            x0a[px] = rx + ix0;
            x1a[px] = rx + ix1;
        }

        float* obase = gout + ((size_t)r * 49 + (size_t)py * POOL) * CH;

#pragma unroll
        for (int px = 0; px < POOL; ++px) {
            const f4 v00 = *(const f4*)(row0 + (size_t)x0a[px] * CH);
            const f4 v01 = *(const f4*)(row0 + (size_t)x1a[px] * CH);
            const f4 v10 = *(const f4*)(row1 + (size_t)x0a[px] * CH);
            const f4 v11 = *(const f4*)(row1 + (size_t)x1a[px] * CH);
            const float tx = txa[px];
            f4 top = v00 + tx * (v01 - v00);
            f4 bot = v10 + tx * (v11 - v10);
            f4 res = top + ty * (bot - top);
            __builtin_nontemporal_store(res, (f4*)(obase + (size_t)px * CH));
        }
    }
}

extern "C" void kernel_launch(void* const* d_in, const int* in_sizes, int n_in,
                              void* d_out, int out_size, void* d_ws, size_t ws_size,
                              hipStream_t stream) {
    const float* img  = (const float*)d_in[0];
    const int*   rois = (const int*)d_in[1];
    float*       out  = (float*)d_out;

    roi_align_kernel<<<NBLK_P, 256, 0, stream>>>(img, rois, out);
}